// Round 9
// baseline (940.609 us; speedup 1.0000x reference)
//
#include <hip/hip_runtime.h>
#include <hip/hip_bf16.h>
#include <stdint.h>
#include <stddef.h>

#define B_DIM   1024
#define DIN     512
#define H_DIM   768
#define A_DIM   5001
#define NHEADS  2
#define NSTEPS  4
#define C_DIM   2
#define NEG_VAL -1e30f
#define BH      (B_DIM * H_DIM)
#define HG      (3 * H_DIM)

typedef unsigned short u16;
typedef __attribute__((ext_vector_type(8))) short v8s;
typedef __attribute__((ext_vector_type(4))) float v4f;

typedef const __attribute__((address_space(1))) uint32_t* gas_ptr;
typedef __attribute__((address_space(3))) uint32_t* las_ptr;

__device__ __forceinline__ void load_lds16(const void* g, void* l) {
  // async global->LDS DMA, 16B per lane; LDS dest is wave-uniform base + lane*16
  __builtin_amdgcn_global_load_lds((gas_ptr)g, (las_ptr)l, 16, 0, 0);
}

// ------------------------- Threefry-2x32 (JAX-compatible) -------------------------
__host__ __device__ inline uint32_t rotl32(uint32_t x, int d) {
  return (x << d) | (x >> (32 - d));
}

__host__ __device__ inline void threefry2x32(uint32_t k0, uint32_t k1,
                                             uint32_t x0, uint32_t x1,
                                             uint32_t& o0, uint32_t& o1) {
  uint32_t ks2 = k0 ^ k1 ^ 0x1BD11BDAu;
  x0 += k0; x1 += k1;
#define TFR(d) { x0 += x1; x1 = rotl32(x1, (d)); x1 ^= x0; }
  TFR(13) TFR(15) TFR(26) TFR(6)  x0 += k1;  x1 += ks2 + 1u;
  TFR(17) TFR(29) TFR(16) TFR(24) x0 += ks2; x1 += k0 + 2u;
  TFR(13) TFR(15) TFR(26) TFR(6)  x0 += k0;  x1 += k1 + 3u;
  TFR(17) TFR(29) TFR(16) TFR(24) x0 += k1;  x1 += ks2 + 4u;
  TFR(13) TFR(15) TFR(26) TFR(6)  x0 += ks2; x1 += k0 + 5u;
#undef TFR
  o0 = x0; o1 = x1;
}

__device__ inline float gumbel_noise(uint32_t k0, uint32_t k1, uint32_t idx) {
  uint32_t o0, o1;
  threefry2x32(k0, k1, 0u, idx, o0, o1);
  uint32_t bits = o0 ^ o1;
  float f = __uint_as_float(0x3f800000u | (bits >> 9)) - 1.0f;   // [0,1)
  float u = fmaxf(1e-9f, f * (1.0f - 1e-9f) + 1e-9f);            // jax.random.uniform
  return -logf(-logf(u));                                        // Gumbel(0,1)
}

// XLA logistic lowering: 0.5 + 0.5 * tanh(0.5 * x)
__device__ inline float sigmoidf_(float x) { return 0.5f * tanhf(0.5f * x) + 0.5f; }

__device__ inline void split_bf16(float x, u16& hi, u16& lo) {
  __hip_bfloat16 h = __float2bfloat16(x);
  float hf = __bfloat162float(h);
  __hip_bfloat16 l = __float2bfloat16(x - hf);
  hi = *(const u16*)&h;
  lo = *(const u16*)&l;
}

// ------------------------- elementwise split: f32 -> bf16 hi/lo -------------------------
__global__ __launch_bounds__(256) void split_kernel(
    const float* __restrict__ in, u16* __restrict__ hi, u16* __restrict__ lo, int n) {
  int idx = blockIdx.x * blockDim.x + threadIdx.x;
  if (idx >= n) return;
  u16 h, l;
  split_bf16(in[idx], h, l);
  hi[idx] = h; lo[idx] = l;
}

// ------------------------- batched weight transpose + bf16 split: W[K][N] -> hi/lo[N][K] -------------------------
struct TS { const float* W; u16* hi; u16* lo; int K; int N; };
struct TS9 { TS t[9]; };

__global__ __launch_bounds__(256) void transpose_split_b(TS9 ts) {
  const TS p = ts.t[blockIdx.z];
  const int k0 = blockIdx.y * 32, n0 = blockIdx.x * 32;
  if (k0 >= p.K || n0 >= p.N) return;
  __shared__ float tile[32][33];
  const int tx = threadIdx.x & 31, ty = threadIdx.x >> 5;
#pragma unroll
  for (int r = ty; r < 32; r += 8) {
    int n = n0 + tx;
    tile[r][tx] = (n < p.N) ? p.W[(size_t)(k0 + r) * p.N + n] : 0.0f;
  }
  __syncthreads();
#pragma unroll
  for (int r = ty; r < 32; r += 8) {
    int n = n0 + r, k = k0 + tx;
    if (n < p.N) {
      u16 h, l;
      split_bf16(tile[tx][r], h, l);
      p.hi[(size_t)n * p.K + k] = h;
      p.lo[(size_t)n * p.K + k] = l;
    }
  }
}

// ------------------------- bf16x3 MFMA GEMM: 128x128 tile, 4 waves, BK=32, single-buffer -------------------------
// (R5-proven core.) Staging via global_load_lds; swizzle involution (rule #21):
// source slot (ln&3)^((lrow>>1)&3), read slot lk^((lm>>1)&3). Split-K via per-slice [k0,k0+klen).
// Per z-slice: N, nbx, ldc, act, optional bias (null -> raw partial), f32 C and/or split Ch/Cl.
struct GemmS {
  const u16* Ah[8]; const u16* Al[8];
  const u16* Bh[8]; const u16* Bl[8];
  const float* bias[8];
  float* C[8];
  u16* Ch[8]; u16* Cl[8];
  int N[8]; int nbx[8]; long long ldc[8]; int act[8]; int dup[8];
  int k0[8]; int klen[8];
};

__global__ __launch_bounds__(256, 2) void gemm_mfma(GemmS gs, int K, int nby) {
  const int e = blockIdx.y;
  // XCD-chunked, m-fastest block ordering (gridDim.x divisible by 8)
  const int nwg = gridDim.x;
  const int chunk = nwg >> 3;
  const int lid = (blockIdx.x & 7) * chunk + (blockIdx.x >> 3);
  const int by = lid % nby;
  const int bx = lid / nby;
  if (bx >= gs.nbx[e]) return;      // variable-shape early exit
  const int bm = by * 128, bn = bx * 128;
  const int N = gs.N[e];
  const int kb = gs.k0[e];
  const int ke = kb + gs.klen[e];

  __shared__ __align__(16) u16 lds[4][128 * 32];  // Ahi, Alo, Bhi, Blo (8KB each)

  const int tid = threadIdx.x;
  const int wv = tid >> 6, ln = tid & 63;
  const int wr = wv >> 1, wc = wv & 1;     // wave 2x2 grid for compute
  const int lk = ln >> 4;                  // k-group 0..3
  const int lm = ln & 15;                  // frag row/col
  const int fswz = (lm >> 1) & 3;          // read-side XOR swizzle

  // staging: wave wv DMAs tensor wv; per issue i rows i*16+(ln>>2)
  const int lrow = ln >> 2;                          // 0..15
  const int slot = (ln & 3) ^ ((lrow >> 1) & 3);     // issue-invariant source swizzle
  const u16* tsrc = (wv == 0) ? gs.Ah[e] : (wv == 1) ? gs.Al[e]
                  : (wv == 2) ? gs.Bh[e] : gs.Bl[e];
  const int isB = (wv >= 2);
  const int rowbase = isB ? bn : bm;

  v4f acc[4][4];
#pragma unroll
  for (int i = 0; i < 4; ++i)
#pragma unroll
    for (int j = 0; j < 4; ++j) acc[i][j] = (v4f){0.f, 0.f, 0.f, 0.f};

  for (int kt = kb; kt < ke; kt += 32) {
#pragma unroll
    for (int i = 0; i < 8; ++i) {
      int gr = rowbase + i * 16 + lrow;
      if (isB && gr >= N) gr = N - 1;      // OOB N rows: duplicate last (C-write guarded)
      const u16* gp = tsrc + (size_t)gr * K + kt + slot * 8;
      load_lds16(gp, (void*)&lds[wv][i * 512]);
    }
    __syncthreads();   // compiler drains vmcnt(0) before barrier (m97 pattern)

    v8s ah[4], al[4], bh[4], bl[4];
#pragma unroll
    for (int mi = 0; mi < 4; ++mi) {
      const int r = wr * 64 + mi * 16 + lm;
      const int off = r * 32 + ((lk ^ fswz) * 8);
      ah[mi] = *(const v8s*)&lds[0][off];
      al[mi] = *(const v8s*)&lds[1][off];
    }
#pragma unroll
    for (int ni = 0; ni < 4; ++ni) {
      const int r = wc * 64 + ni * 16 + lm;
      const int off = r * 32 + ((lk ^ fswz) * 8);
      bh[ni] = *(const v8s*)&lds[2][off];
      bl[ni] = *(const v8s*)&lds[3][off];
    }
    // 3-term split product
#pragma unroll
    for (int mi = 0; mi < 4; ++mi)
#pragma unroll
      for (int ni = 0; ni < 4; ++ni)
        acc[mi][ni] = __builtin_amdgcn_mfma_f32_16x16x32_bf16(ah[mi], bh[ni], acc[mi][ni], 0, 0, 0);
#pragma unroll
    for (int mi = 0; mi < 4; ++mi)
#pragma unroll
      for (int ni = 0; ni < 4; ++ni)
        acc[mi][ni] = __builtin_amdgcn_mfma_f32_16x16x32_bf16(ah[mi], bl[ni], acc[mi][ni], 0, 0, 0);
#pragma unroll
    for (int mi = 0; mi < 4; ++mi)
#pragma unroll
      for (int ni = 0; ni < 4; ++ni)
        acc[mi][ni] = __builtin_amdgcn_mfma_f32_16x16x32_bf16(al[mi], bh[ni], acc[mi][ni], 0, 0, 0);

    __syncthreads();   // protect LDS before next tile's DMA
  }

  // epilogue: C/D layout col=lane&15, row=(lane>>4)*4+reg (m89-verified)
  const float* bias = gs.bias[e];
  const long long ldc = gs.ldc[e];
  const int act = gs.act[e];
  float* Cf = gs.C[e];
  u16* ch = gs.Ch[e]; u16* cl = gs.Cl[e];
  const int dup = gs.dup[e];
#pragma unroll
  for (int mi = 0; mi < 4; ++mi) {
    const int m = bm + wr * 64 + mi * 16 + lk * 4;
#pragma unroll
    for (int ni = 0; ni < 4; ++ni) {
      const int n = bn + wc * 64 + ni * 16 + lm;
      if (n < N) {
        const float bv = bias ? bias[n] : 0.0f;
#pragma unroll
        for (int r = 0; r < 4; ++r) {
          float v = acc[mi][ni][r] + bv;
          if (act) v = fmaxf(v, 0.0f);
          const size_t ix = (size_t)(m + r) * ldc + n;
          if (Cf) Cf[ix] = v;
          if (ch) {
            u16 hh, ll;
            split_bf16(v, hh, ll);
            ch[ix] = hh; cl[ix] = ll;
            if (dup) { ch[ix + (size_t)BH] = hh; cl[ix + (size_t)BH] = ll; }
          }
        }
      }
    }
  }
}

// ------------------------- GRU combine, j=0: gi = p0+p1 (bias in p0); gh == bhh -------------------------
__global__ __launch_bounds__(256) void gru_combine_first(
    const float* __restrict__ gip, const float* __restrict__ gbhh, float* __restrict__ h2,
    u16* __restrict__ h_hi, u16* __restrict__ h_lo) {
  int idx = blockIdx.x * blockDim.x + threadIdx.x;
  if (idx >= 2 * BH) return;
  int e = idx / BH, rem = idx % BH;
  int b = rem / H_DIM, c = rem - b * H_DIM;
  const float* g0 = gip + ((size_t)(0 * 2 + e) * B_DIM + b) * HG;
  const float* g1 = gip + ((size_t)(1 * 2 + e) * B_DIM + b) * HG;
  const float* bb = gbhh + (size_t)e * HG;
  float ir = g0[c] + g1[c];
  float iz = g0[H_DIM + c] + g1[H_DIM + c];
  float inn = g0[2 * H_DIM + c] + g1[2 * H_DIM + c];
  float hr = bb[c], hz = bb[H_DIM + c], hn = bb[2 * H_DIM + c];
  float r = sigmoidf_(ir + hr);
  float z = sigmoidf_(iz + hz);
  float n = tanhf(inn + r * hn);
  float hv = (1.0f - z) * n + z * 0.0f;
  h2[idx] = hv;
  u16 h, l;
  split_bf16(hv, h, l);
  h_hi[idx] = h; h_lo[idx] = l;
}

// ------------------------- GRU gate combine: gi = gip0+gip1, gh = ghp0+ghp1 (biases in p0) -------------------------
__global__ __launch_bounds__(256) void gru_combine_kernel(
    const float* __restrict__ gip, const float* __restrict__ ghp, float* __restrict__ h2,
    u16* __restrict__ h_hi, u16* __restrict__ h_lo) {
  int idx = blockIdx.x * blockDim.x + threadIdx.x;
  if (idx >= 2 * BH) return;
  int e = idx / BH, rem = idx % BH;
  int b = rem / H_DIM, c = rem - b * H_DIM;
  const float* gi0 = gip + ((size_t)(0 * 2 + e) * B_DIM + b) * HG;
  const float* gi1 = gip + ((size_t)(1 * 2 + e) * B_DIM + b) * HG;
  const float* gh0 = ghp + ((size_t)(0 * 2 + e) * B_DIM + b) * HG;
  const float* gh1 = ghp + ((size_t)(1 * 2 + e) * B_DIM + b) * HG;
  float ir = gi0[c] + gi1[c];
  float iz = gi0[H_DIM + c] + gi1[H_DIM + c];
  float inn = gi0[2 * H_DIM + c] + gi1[2 * H_DIM + c];
  float hr = gh0[c] + gh1[c];
  float hz = gh0[H_DIM + c] + gh1[H_DIM + c];
  float hn = gh0[2 * H_DIM + c] + gh1[2 * H_DIM + c];
  float r = sigmoidf_(ir + hr);
  float z = sigmoidf_(iz + hz);
  float n = tanhf(inn + r * hn);
  float hv = (1.0f - z) * n + z * h2[idx];
  h2[idx] = hv;
  u16 h, l;
  split_bf16(hv, h, l);
  h_hi[idx] = h; h_lo[idx] = l;
}

// ------------------------- sampling (both heads): logits = lp0+lp1 (bias in lp0) + fused cur_in -------------------------
#define STH 256
#define PER_TH 20  // ceil(5001/256)

__global__ __launch_bounds__(STH) void sample_kernel(
    const float* __restrict__ lp, float* __restrict__ probs, const int* __restrict__ x_mask,
    int* __restrict__ indb, int j, uint4 keys,
    const float* __restrict__ cls, const float* __restrict__ ae_w,
    u16* __restrict__ cur_hi, u16* __restrict__ cur_lo, int docur) {
  int b = blockIdx.x;
  int e = blockIdx.y;
  int t = threadIdx.x;
  uint32_t k0 = (e == 0) ? keys.x : keys.z;
  uint32_t k1 = (e == 0) ? keys.y : keys.w;
  __shared__ float rv[STH];
  __shared__ int ri[STH];
  __shared__ int s_ind;

  const float* l0 = lp + ((size_t)(0 * 2 + e) * B_DIM + b) * A_DIM;
  const float* l1 = lp + ((size_t)(1 * 2 + e) * B_DIM + b) * A_DIM;
  float* prow = probs + (((size_t)b * NHEADS + e) * NSTEPS + j) * A_DIM;
  const int* mrow = x_mask + (size_t)b * A_DIM;

  int prev[3];
  bool dead = false;
  for (int tt = 0; tt < j; ++tt) {
    prev[tt] = indb[(e * NSTEPS + tt) * B_DIM + b];
    if (prev[tt] == 0) dead = true;
  }

  bool rowany = true;
  if (j == 0) {
    int any = 0;
    for (int a = t; a < A_DIM; a += STH) any |= mrow[a];
    ri[t] = any; __syncthreads();
    for (int s = STH / 2; s > 0; s >>= 1) {
      if (t < s) ri[t] |= ri[t + s];
      __syncthreads();
    }
    rowany = (ri[0] != 0);
    __syncthreads();
  }

  float v[PER_TH];
  float lmax = -3.0e38f;
#pragma unroll
  for (int s = 0; s < PER_TH; ++s) {
    int a = t + s * STH;
    float val = -3.0e38f;
    if (a < A_DIM) {
      int m;
      if (j == 0) {
        m = (a == 0) ? (rowany ? mrow[0] : 1) : mrow[a];
      } else if (a == 0) {
        m = 1;
      } else if (dead) {
        m = 0;
      } else {
        m = mrow[a];
        if (m) {
          for (int tt = 0; tt < j; ++tt)
            if (prev[tt] == a) { m = 0; break; }
        }
      }
      if (m > 0)
        val = l0[a] + l1[a] + gumbel_noise(k0, k1, (uint32_t)(b * A_DIM + a));
    }
    v[s] = val;
    lmax = fmaxf(lmax, val);
  }

  rv[t] = lmax; __syncthreads();
  for (int s = STH / 2; s > 0; s >>= 1) {
    if (t < s) rv[t] = fmaxf(rv[t], rv[t + s]);
    __syncthreads();
  }
  float m = rv[0]; __syncthreads();

  float lsum = 0.0f;
#pragma unroll
  for (int s = 0; s < PER_TH; ++s) {
    int a = t + s * STH;
    float ev = (a < A_DIM && v[s] > -1.0e37f) ? expf(v[s] - m) : 0.0f;
    v[s] = ev; lsum += ev;
  }
  rv[t] = lsum; __syncthreads();
  for (int s = STH / 2; s > 0; s >>= 1) {
    if (t < s) rv[t] += rv[t + s];
    __syncthreads();
  }
  float ssum = rv[0]; __syncthreads();

  float besty = -1.0f; int besti = A_DIM;
#pragma unroll
  for (int s = 0; s < PER_TH; ++s) {
    int a = t + s * STH;
    if (a < A_DIM) {
      float y = v[s] / ssum;
      if (y > besty) { besty = y; besti = a; }
    }
  }
  rv[t] = besty; ri[t] = besti; __syncthreads();
  for (int s = STH / 2; s > 0; s >>= 1) {
    if (t < s) {
      float y2 = rv[t + s]; int i2 = ri[t + s];
      if (y2 > rv[t] || (y2 == rv[t] && i2 < ri[t])) { rv[t] = y2; ri[t] = i2; }
    }
    __syncthreads();
  }
  if (t == 0) { s_ind = ri[0]; indb[(e * NSTEPS + j) * B_DIM + b] = ri[0]; }
  __syncthreads();
  int ind = s_ind;

  for (int a = t; a < A_DIM; a += STH) prow[a] = (a == ind) ? 1.0f : 0.0f;

  // fused cur_in = cls + ae_w[ind], split to bf16 hi/lo (next step's GEMM A operand)
  if (docur) {
    const float* crow = cls + (size_t)b * H_DIM;
    const float* arow = ae_w + (size_t)ind * H_DIM;
    u16* chh = cur_hi + (size_t)e * BH + (size_t)b * H_DIM;
    u16* cll = cur_lo + (size_t)e * BH + (size_t)b * H_DIM;
    for (int c = t; c < H_DIM; c += STH) {
      float vv = crow[c] + arow[c];
      u16 hh, ll;
      split_bf16(vv, hh, ll);
      chh[c] = hh; cll[c] = ll;
    }
  }
}

// ------------------------- per-head consequent estimator (both heads) -------------------------
__global__ __launch_bounds__(256) void head_final_kernel(
    const int* __restrict__ indb, const float* __restrict__ Wmu,
    const float* __restrict__ bmu, const float* __restrict__ Wcov,
    const float* __restrict__ bcov, const float* __restrict__ alpha,
    float* __restrict__ matcp) {
  int idx = blockIdx.x * blockDim.x + threadIdx.x;
  if (idx >= NHEADS * B_DIM) return;
  int e = idx / B_DIM, b = idx - e * B_DIM;
  float a0 = 0.0f, a1 = 0.0f, ac = 0.0f;
  for (int j = 0; j < NSTEPS; ++j) {
    int ind = indb[(e * NSTEPS + j) * B_DIM + b];
    a0 += 0.25f * Wmu[(size_t)ind * C_DIM + 0];
    a1 += 0.25f * Wmu[(size_t)ind * C_DIM + 1];
    ac += 0.25f * Wcov[ind];
  }
  float mu0 = sigmoidf_(a0 + bmu[0]);
  float mu1 = sigmoidf_(a1 + bmu[1]);
  float cov = sigmoidf_(ac + bcov[0]);
  float n = cov * 56000.0f;
  float sf = alpha[0] / n;
  float denom = 1.0f + 2.0f * sf;
  matcp[((size_t)b * NHEADS + e) * C_DIM + 0] = (mu0 + sf) / denom;
  matcp[((size_t)b * NHEADS + e) * C_DIM + 1] = (mu1 + sf) / denom;
}

__global__ __launch_bounds__(256) void final_out_kernel(
    const float* __restrict__ matcp, float* __restrict__ out) {
  int idx = blockIdx.x * blockDim.x + threadIdx.x;
  if (idx >= B_DIM * C_DIM) return;
  int b = idx / C_DIM, c = idx - b * C_DIM;
  float s = matcp[((size_t)b * NHEADS + 0) * C_DIM + c] +
            matcp[((size_t)b * NHEADS + 1) * C_DIM + c];
  out[idx] = logf(s * 0.5f);
}

// ------------------------- orchestration -------------------------
extern "C" void kernel_launch(void* const* d_in, const int* in_sizes, int n_in,
                              void* d_out, int out_size, void* d_ws, size_t ws_size,
                              hipStream_t stream) {
  const float* x     = (const float*)d_in[0];
  const int*   xmask = (const int*)d_in[1];
  const float* W1 = (const float*)d_in[2];  const float* b1 = (const float*)d_in[3];
  const float* W2 = (const float*)d_in[4];  const float* b2 = (const float*)d_in[5];
  const float* W3 = (const float*)d_in[6];  const float* b3 = (const float*)d_in[7];
  const float* gWih = (const float*)d_in[8];  const float* gWhh = (const float*)d_in[9];
  const float* gbih = (const float*)d_in[10]; const float* gbhh = (const float*)d_in[11];
  const float* hW = (const float*)d_in[12];   const float* hb = (const float*)d_in[13];
  const float* ae_w = (const float*)d_in[14];
  const float* Wmu  = (const float*)d_in[15]; const float* bmu  = (const float*)d_in[16];
  const float* Wcov = (const float*)d_in[17]; const float* bcov = (const float*)d_in[18];
  const float* alpha = (const float*)d_in[19];

  float* out = (float*)d_out;
  float* probs = out + (size_t)B_DIM * C_DIM;                       // [B, 2, 4, A]
  float* matcp = probs + (size_t)B_DIM * NHEADS * NSTEPS * A_DIM;   // [B, 2, C]

  uint8_t* wsp = (uint8_t*)d_ws;
  auto alloc = [&](size_t bytes) {
    uint8_t* p = wsp;
    wsp += (bytes + 255) & ~(size_t)255;
    return p;
  };
  float* cls  = (float*)alloc((size_t)BH * 4);
  float* h2   = (float*)alloc((size_t)2 * BH * 4);
  float* gi2  = (float*)alloc((size_t)4 * B_DIM * HG * 4);   // [2 chunks][2 heads][B][HG]
  float* gh2  = (float*)alloc((size_t)4 * B_DIM * HG * 4);   // [2 chunks][2 heads][B][HG]
  float* lp   = (float*)alloc((size_t)4 * B_DIM * A_DIM * 4); // [2 chunks][2 heads][B][A]
  u16* h_hi   = (u16*)alloc((size_t)2 * BH * 2);
  u16* h_lo   = (u16*)alloc((size_t)2 * BH * 2);
  u16* cur_hi = (u16*)alloc((size_t)2 * BH * 2);
  u16* cur_lo = (u16*)alloc((size_t)2 * BH * 2);
  u16* WihT_h = (u16*)alloc((size_t)2 * HG * H_DIM * 2);
  u16* WihT_l = (u16*)alloc((size_t)2 * HG * H_DIM * 2);
  u16* WhhT_h = (u16*)alloc((size_t)2 * HG * H_DIM * 2);
  u16* WhhT_l = (u16*)alloc((size_t)2 * HG * H_DIM * 2);
  u16* hWT_h  = (u16*)alloc((size_t)2 * A_DIM * H_DIM * 2);
  u16* hWT_l  = (u16*)alloc((size_t)2 * A_DIM * H_DIM * 2);
  u16* x_hi   = (u16*)alloc((size_t)B_DIM * DIN * 2);
  u16* x_lo   = (u16*)alloc((size_t)B_DIM * DIN * 2);
  u16* t1_hi  = (u16*)alloc((size_t)BH * 2);
  u16* t1_lo  = (u16*)alloc((size_t)BH * 2);
  u16* t2_hi  = (u16*)alloc((size_t)BH * 2);
  u16* t2_lo  = (u16*)alloc((size_t)BH * 2);
  u16* W1T_h  = (u16*)alloc((size_t)H_DIM * DIN * 2);
  u16* W1T_l  = (u16*)alloc((size_t)H_DIM * DIN * 2);
  u16* W2T_h  = (u16*)alloc((size_t)H_DIM * H_DIM * 2);
  u16* W2T_l  = (u16*)alloc((size_t)H_DIM * H_DIM * 2);
  u16* W3T_h  = (u16*)alloc((size_t)H_DIM * H_DIM * 2);
  u16* W3T_l  = (u16*)alloc((size_t)H_DIM * H_DIM * 2);
  int* indb   = (int*)alloc((size_t)NHEADS * NSTEPS * B_DIM * 4);

  dim3 blk(256);

  // ---- one-time prep: all 9 weight transposes in one launch + x split ----
  {
    TS9 ts;
    ts.t[0] = {gWih,                    WihT_h,                    WihT_l,                    H_DIM, HG};
    ts.t[1] = {gWih + (size_t)H_DIM*HG, WihT_h + (size_t)HG*H_DIM, WihT_l + (size_t)HG*H_DIM, H_DIM, HG};
    ts.t[2] = {gWhh,                    WhhT_h,                    WhhT_l,                    H_DIM, HG};
    ts.t[3] = {gWhh + (size_t)H_DIM*HG, WhhT_h + (size_t)HG*H_DIM, WhhT_l + (size_t)HG*H_DIM, H_DIM, HG};
    ts.t[4] = {hW,                          hWT_h,                           hWT_l,                           H_DIM, A_DIM};
    ts.t[5] = {hW + (size_t)H_DIM*A_DIM,    hWT_h + (size_t)A_DIM*H_DIM,     hWT_l + (size_t)A_DIM*H_DIM,     H_DIM, A_DIM};
    ts.t[6] = {W1, W1T_h, W1T_l, DIN,   H_DIM};
    ts.t[7] = {W2, W2T_h, W2T_l, H_DIM, H_DIM};
    ts.t[8] = {W3, W3T_h, W3T_l, H_DIM, H_DIM};
    transpose_split_b<<<dim3((A_DIM + 31) / 32, H_DIM / 32, 9), blk, 0, stream>>>(ts);
  }
  split_kernel<<<(B_DIM * DIN + 255) / 256, blk, 0, stream>>>(x, x_hi, x_lo, B_DIM * DIN);

  auto setE = [](GemmS& g, int e, const u16* ah, const u16* al, const u16* bhp, const u16* blp,
                 const float* bias, float* Cf, u16* chp, u16* clp,
                 int N, int nbx, long long ldc, int act, int dup, int k0, int klen) {
    g.Ah[e] = ah; g.Al[e] = al; g.Bh[e] = bhp; g.Bl[e] = blp;
    g.bias[e] = bias; g.C[e] = Cf; g.Ch[e] = chp; g.Cl[e] = clp;
    g.N[e] = N; g.nbx[e] = nbx; g.ldc[e] = ldc; g.act[e] = act; g.dup[e] = dup;
    g.k0[e] = k0; g.klen[e] = klen;
  };

  // ---- MLP via bf16x3 MFMA, fused bias/relu/split epilogues; MLP3 also fuses cur=cls init ----
  {
    GemmS g{};
    setE(g, 0, x_hi, x_lo, W1T_h, W1T_l, b1, nullptr, t1_hi, t1_lo, H_DIM, H_DIM / 128, H_DIM, 1, 0, 0, DIN);
    gemm_mfma<<<dim3((H_DIM / 128) * 8, 1), blk, 0, stream>>>(g, DIN, 8);
  }
  {
    GemmS g{};
    setE(g, 0, t1_hi, t1_lo, W2T_h, W2T_l, b2, nullptr, t2_hi, t2_lo, H_DIM, H_DIM / 128, H_DIM, 1, 0, 0, H_DIM);
    gemm_mfma<<<dim3((H_DIM / 128) * 8, 1), blk, 0, stream>>>(g, H_DIM, 8);
  }
  {
    GemmS g{};
    // writes cls (f32) AND cur_hi/lo for head0 (+dup to head1) — replaces init_state
    setE(g, 0, t2_hi, t2_lo, W3T_h, W3T_l, b3, cls, cur_hi, cur_lo, H_DIM, H_DIM / 128, H_DIM, 0, 1, 0, H_DIM);
    gemm_mfma<<<dim3((H_DIM / 128) * 8, 1), blk, 0, stream>>>(g, H_DIM, 8);
  }

  // host-side key schedule: key(42) -> fold_in(head) -> fold_in(step)
  uint32_t bk0 = 0u, bk1 = 42u;
  uint32_t hk[2][2];
  threefry2x32(bk0, bk1, 0u, 0u, hk[0][0], hk[0][1]);
  threefry2x32(bk0, bk1, 0u, 1u, hk[1][0], hk[1][1]);

  const int NBX_L = (A_DIM + 127) / 128;  // 40
  const int NBX_G = HG / 128;             // 18
  const int KH = H_DIM / 2;               // 384 split-K chunk

  for (int j = 0; j < NSTEPS; ++j) {
    // ---- gates GEMM, split-K x2. j=0: gi only (4 slices); else gi+gh (8 slices) ----
    if (j == 0) {
      GemmS g{};
      for (int head = 0; head < NHEADS; ++head)
        for (int c = 0; c < 2; ++c)
          setE(g, head * 2 + c, cur_hi + (size_t)head * BH, cur_lo + (size_t)head * BH,
               WihT_h + (size_t)head * HG * H_DIM, WihT_l + (size_t)head * HG * H_DIM,
               c == 0 ? gbih + (size_t)head * HG : nullptr,
               gi2 + (size_t)(c * 2 + head) * B_DIM * HG, nullptr, nullptr,
               HG, NBX_G, HG, 0, 0, c * KH, KH);
      gemm_mfma<<<dim3(NBX_G * 8, 4), blk, 0, stream>>>(g, H_DIM, 8);
      gru_combine_first<<<(2 * BH + 255) / 256, blk, 0, stream>>>(gi2, gbhh, h2, h_hi, h_lo);
    } else {
      GemmS g{};
      for (int head = 0; head < NHEADS; ++head)
        for (int src = 0; src < 2; ++src)
          for (int c = 0; c < 2; ++c) {
            const u16* ah = src ? h_hi + (size_t)head * BH : cur_hi + (size_t)head * BH;
            const u16* al = src ? h_lo + (size_t)head * BH : cur_lo + (size_t)head * BH;
            const u16* bhp = (src ? WhhT_h : WihT_h) + (size_t)head * HG * H_DIM;
            const u16* blp = (src ? WhhT_l : WihT_l) + (size_t)head * HG * H_DIM;
            const float* bias = c ? nullptr
                                  : (src ? gbhh : gbih) + (size_t)head * HG;
            float* Cf = (src ? gh2 : gi2) + (size_t)(c * 2 + head) * B_DIM * HG;
            setE(g, ((head * 2 + src) << 1) | c, ah, al, bhp, blp, bias, Cf,
                 nullptr, nullptr, HG, NBX_G, HG, 0, 0, c * KH, KH);
          }
      gemm_mfma<<<dim3(NBX_G * 8, 8), blk, 0, stream>>>(g, H_DIM, 8);
      gru_combine_kernel<<<(2 * BH + 255) / 256, blk, 0, stream>>>(gi2, gh2, h2, h_hi, h_lo);
    }

    // ---- logits GEMM, split-K x2 (4 slices): raw partials into lp; bias hb in chunk 0 ----
    {
      GemmS g{};
      for (int head = 0; head < NHEADS; ++head)
        for (int c = 0; c < 2; ++c)
          setE(g, head * 2 + c, h_hi + (size_t)head * BH, h_lo + (size_t)head * BH,
               hWT_h + (size_t)head * A_DIM * H_DIM, hWT_l + (size_t)head * A_DIM * H_DIM,
               c == 0 ? hb + (size_t)head * A_DIM : nullptr,
               lp + (size_t)(c * 2 + head) * B_DIM * A_DIM, nullptr, nullptr,
               A_DIM, NBX_L, A_DIM, 0, 0, c * KH, KH);
      gemm_mfma<<<dim3(NBX_L * 8, 4), blk, 0, stream>>>(g, H_DIM, 8);
    }

    // ---- sample (sums lp chunks) + fused cur update ----
    uint32_t s00, s01, s10, s11;
    threefry2x32(hk[0][0], hk[0][1], 0u, (uint32_t)j, s00, s01);
    threefry2x32(hk[1][0], hk[1][1], 0u, (uint32_t)j, s10, s11);
    uint4 keys; keys.x = s00; keys.y = s01; keys.z = s10; keys.w = s11;
    sample_kernel<<<dim3(B_DIM, NHEADS), dim3(STH), 0, stream>>>(
        lp, probs, xmask, indb, j, keys, cls, ae_w, cur_hi, cur_lo, (j < NSTEPS - 1) ? 1 : 0);
  }

  head_final_kernel<<<(NHEADS * B_DIM + 255) / 256, blk, 0, stream>>>(
      indb, Wmu, bmu, Wcov, bcov, alpha, matcp);
  final_out_kernel<<<(B_DIM * C_DIM + 255) / 256, blk, 0, stream>>>(matcp, out);
}

// Round 10
// 864.017 us; speedup vs baseline: 1.0886x; 1.0886x over previous
//
#include <hip/hip_runtime.h>
#include <hip/hip_bf16.h>
#include <stdint.h>
#include <stddef.h>

#define B_DIM   1024
#define DIN     512
#define H_DIM   768
#define A_DIM   5001
#define NHEADS  2
#define NSTEPS  4
#define C_DIM   2
#define NEG_VAL -1e30f
#define BH      (B_DIM * H_DIM)
#define HG      (3 * H_DIM)

typedef unsigned short u16;
typedef __attribute__((ext_vector_type(8))) short v8s;
typedef __attribute__((ext_vector_type(4))) float v4f;

typedef const __attribute__((address_space(1))) uint32_t* gas_ptr;
typedef __attribute__((address_space(3))) uint32_t* las_ptr;

__device__ __forceinline__ void load_lds16(const void* g, void* l) {
  // async global->LDS DMA, 16B per lane; LDS dest is wave-uniform base + lane*16
  __builtin_amdgcn_global_load_lds((gas_ptr)g, (las_ptr)l, 16, 0, 0);
}

// ------------------------- Threefry-2x32 (JAX-compatible) -------------------------
__host__ __device__ inline uint32_t rotl32(uint32_t x, int d) {
  return (x << d) | (x >> (32 - d));
}

__host__ __device__ inline void threefry2x32(uint32_t k0, uint32_t k1,
                                             uint32_t x0, uint32_t x1,
                                             uint32_t& o0, uint32_t& o1) {
  uint32_t ks2 = k0 ^ k1 ^ 0x1BD11BDAu;
  x0 += k0; x1 += k1;
#define TFR(d) { x0 += x1; x1 = rotl32(x1, (d)); x1 ^= x0; }
  TFR(13) TFR(15) TFR(26) TFR(6)  x0 += k1;  x1 += ks2 + 1u;
  TFR(17) TFR(29) TFR(16) TFR(24) x0 += ks2; x1 += k0 + 2u;
  TFR(13) TFR(15) TFR(26) TFR(6)  x0 += k0;  x1 += k1 + 3u;
  TFR(17) TFR(29) TFR(16) TFR(24) x0 += k1;  x1 += ks2 + 4u;
  TFR(13) TFR(15) TFR(26) TFR(6)  x0 += ks2; x1 += k0 + 5u;
#undef TFR
  o0 = x0; o1 = x1;
}

__device__ inline float gumbel_noise(uint32_t k0, uint32_t k1, uint32_t idx) {
  uint32_t o0, o1;
  threefry2x32(k0, k1, 0u, idx, o0, o1);
  uint32_t bits = o0 ^ o1;
  float f = __uint_as_float(0x3f800000u | (bits >> 9)) - 1.0f;   // [0,1)
  float u = fmaxf(1e-9f, f * (1.0f - 1e-9f) + 1e-9f);            // jax.random.uniform
  return -logf(-logf(u));                                        // Gumbel(0,1)
}

// XLA logistic lowering: 0.5 + 0.5 * tanh(0.5 * x)
__device__ inline float sigmoidf_(float x) { return 0.5f * tanhf(0.5f * x) + 0.5f; }

__device__ inline void split_bf16(float x, u16& hi, u16& lo) {
  __hip_bfloat16 h = __float2bfloat16(x);
  float hf = __bfloat162float(h);
  __hip_bfloat16 l = __float2bfloat16(x - hf);
  hi = *(const u16*)&h;
  lo = *(const u16*)&l;
}

// ------------------------- elementwise split: f32 -> bf16 hi/lo -------------------------
__global__ __launch_bounds__(256) void split_kernel(
    const float* __restrict__ in, u16* __restrict__ hi, u16* __restrict__ lo, int n) {
  int idx = blockIdx.x * blockDim.x + threadIdx.x;
  if (idx >= n) return;
  u16 h, l;
  split_bf16(in[idx], h, l);
  hi[idx] = h; lo[idx] = l;
}

// ------------------------- batched weight transpose + bf16 split: W[K][N] -> hi/lo[N][K] -------------------------
struct TS { const float* W; u16* hi; u16* lo; int K; int N; };
struct TS9 { TS t[9]; };

__global__ __launch_bounds__(256) void transpose_split_b(TS9 ts) {
  const TS p = ts.t[blockIdx.z];
  const int k0 = blockIdx.y * 32, n0 = blockIdx.x * 32;
  if (k0 >= p.K || n0 >= p.N) return;
  __shared__ float tile[32][33];
  const int tx = threadIdx.x & 31, ty = threadIdx.x >> 5;
#pragma unroll
  for (int r = ty; r < 32; r += 8) {
    int n = n0 + tx;
    tile[r][tx] = (n < p.N) ? p.W[(size_t)(k0 + r) * p.N + n] : 0.0f;
  }
  __syncthreads();
#pragma unroll
  for (int r = ty; r < 32; r += 8) {
    int n = n0 + r, k = k0 + tx;
    if (n < p.N) {
      u16 h, l;
      split_bf16(tile[tx][r], h, l);
      p.hi[(size_t)n * p.K + k] = h;
      p.lo[(size_t)n * p.K + k] = l;
    }
  }
}

// ------------------------- bf16x3 MFMA GEMM: 128x64 tile, 4 waves, BK=32, single-buffer -------------------------
// R5-proven core with halved N-tile for grid-level parallelism (latency hiding via TLP).
// Staging via global_load_lds; swizzle involution (rule #21): source slot (ln&3)^((lrow>>1)&3),
// read slot lk^((lm>>1)&3). Wave (wr,wc): wr = m-half (64 rows), wc = n-half (32 cols).
struct GemmS {
  const u16* Ah[4]; const u16* Al[4];
  const u16* Bh[4]; const u16* Bl[4];
  const float* bias[4];
  float* C[4];
  u16* Ch[4]; u16* Cl[4];
  int N[4]; int nbx[4]; long long ldc[4]; int act[4]; int dup[4];
};

__global__ __launch_bounds__(256, 4) void gemm_mfma(GemmS gs, int K, int nby) {
  const int e = blockIdx.y;
  // XCD-chunked, m-fastest block ordering (gridDim.x divisible by 8)
  const int nwg = gridDim.x;
  const int chunk = nwg >> 3;
  const int lid = (blockIdx.x & 7) * chunk + (blockIdx.x >> 3);
  const int by = lid % nby;
  const int bx = lid / nby;
  if (bx >= gs.nbx[e]) return;      // variable-shape early exit
  const int bm = by * 128, bn = bx * 64;
  const int N = gs.N[e];

  __shared__ __align__(16) u16 ldsA[2][128 * 32];  // Ahi, Alo (8KB each)
  __shared__ __align__(16) u16 ldsB[2][64 * 32];   // Bhi, Blo (4KB each)

  const int tid = threadIdx.x;
  const int wv = tid >> 6, ln = tid & 63;
  const int wr = wv >> 1, wc = wv & 1;     // wave: m-half (64 rows) x n-half (32 cols)
  const int lk = ln >> 4;                  // k-group 0..3
  const int lm = ln & 15;                  // frag row/col
  const int fswz = (lm >> 1) & 3;          // read-side XOR swizzle

  // staging: wave wv DMAs tensor wv; per issue i rows i*16+(ln>>2)
  const int lrow = ln >> 2;                          // 0..15
  const int slot = (ln & 3) ^ ((lrow >> 1) & 3);     // issue-invariant source swizzle
  const u16* tsrc = (wv == 0) ? gs.Ah[e] : (wv == 1) ? gs.Al[e]
                  : (wv == 2) ? gs.Bh[e] : gs.Bl[e];
  const int isB = (wv >= 2);
  const int rowbase = isB ? bn : bm;
  u16* ldst = isB ? ldsB[wv - 2] : ldsA[wv];
  const int nIss = isB ? 4 : 8;            // B tile has 64 rows, A tile 128

  v4f acc[4][2];
#pragma unroll
  for (int i = 0; i < 4; ++i)
#pragma unroll
    for (int j = 0; j < 2; ++j) acc[i][j] = (v4f){0.f, 0.f, 0.f, 0.f};

  for (int kt = 0; kt < K; kt += 32) {
    for (int i = 0; i < nIss; ++i) {
      int gr = rowbase + i * 16 + lrow;
      if (isB && gr >= N) gr = N - 1;      // OOB N rows: duplicate last (C-write guarded)
      const u16* gp = tsrc + (size_t)gr * K + kt + slot * 8;
      load_lds16(gp, (void*)&ldst[i * 512]);
    }
    __syncthreads();   // compiler drains vmcnt(0) before barrier (m97 pattern)

    v8s ah[4], al[4], bh[2], bl[2];
#pragma unroll
    for (int mi = 0; mi < 4; ++mi) {
      const int r = wr * 64 + mi * 16 + lm;
      const int off = r * 32 + ((lk ^ fswz) * 8);
      ah[mi] = *(const v8s*)&ldsA[0][off];
      al[mi] = *(const v8s*)&ldsA[1][off];
    }
#pragma unroll
    for (int ni = 0; ni < 2; ++ni) {
      const int r = wc * 32 + ni * 16 + lm;
      const int off = r * 32 + ((lk ^ fswz) * 8);
      bh[ni] = *(const v8s*)&ldsB[0][off];
      bl[ni] = *(const v8s*)&ldsB[1][off];
    }
    // 3-term split product
#pragma unroll
    for (int mi = 0; mi < 4; ++mi)
#pragma unroll
      for (int ni = 0; ni < 2; ++ni)
        acc[mi][ni] = __builtin_amdgcn_mfma_f32_16x16x32_bf16(ah[mi], bh[ni], acc[mi][ni], 0, 0, 0);
#pragma unroll
    for (int mi = 0; mi < 4; ++mi)
#pragma unroll
      for (int ni = 0; ni < 2; ++ni)
        acc[mi][ni] = __builtin_amdgcn_mfma_f32_16x16x32_bf16(ah[mi], bl[ni], acc[mi][ni], 0, 0, 0);
#pragma unroll
    for (int mi = 0; mi < 4; ++mi)
#pragma unroll
      for (int ni = 0; ni < 2; ++ni)
        acc[mi][ni] = __builtin_amdgcn_mfma_f32_16x16x32_bf16(al[mi], bh[ni], acc[mi][ni], 0, 0, 0);

    __syncthreads();   // protect LDS before next tile's DMA
  }

  // epilogue: C/D layout col=lane&15, row=(lane>>4)*4+reg (m89-verified)
  const float* bias = gs.bias[e];
  const long long ldc = gs.ldc[e];
  const int act = gs.act[e];
  float* Cf = gs.C[e];
  u16* ch = gs.Ch[e]; u16* cl = gs.Cl[e];
  const int dup = gs.dup[e];
#pragma unroll
  for (int mi = 0; mi < 4; ++mi) {
    const int m = bm + wr * 64 + mi * 16 + lk * 4;
#pragma unroll
    for (int ni = 0; ni < 2; ++ni) {
      const int n = bn + wc * 32 + ni * 16 + lm;
      if (n < N) {
        const float bv = bias[n];
#pragma unroll
        for (int r = 0; r < 4; ++r) {
          float v = acc[mi][ni][r] + bv;
          if (act) v = fmaxf(v, 0.0f);
          const size_t ix = (size_t)(m + r) * ldc + n;
          if (Cf) Cf[ix] = v;
          if (ch) {
            u16 hh, ll;
            split_bf16(v, hh, ll);
            ch[ix] = hh; cl[ix] = ll;
            if (dup) { ch[ix + (size_t)BH] = hh; cl[ix + (size_t)BH] = ll; }
          }
        }
      }
    }
  }
}

// ------------------------- GRU combine, j=0: gh == bhh exactly (h=0) -------------------------
__global__ __launch_bounds__(256) void gru_combine_first(
    const float* __restrict__ gi2, const float* __restrict__ gbhh, float* __restrict__ h2,
    u16* __restrict__ h_hi, u16* __restrict__ h_lo) {
  int idx = blockIdx.x * blockDim.x + threadIdx.x;
  if (idx >= 2 * BH) return;
  int e = idx / BH, rem = idx % BH;
  int b = rem / H_DIM, c = rem - b * H_DIM;
  const float* gib = gi2 + ((size_t)e * B_DIM + b) * HG;
  const float* bb = gbhh + (size_t)e * HG;
  float ir = gib[c], iz = gib[H_DIM + c], inn = gib[2 * H_DIM + c];
  float hr = bb[c], hz = bb[H_DIM + c], hn = bb[2 * H_DIM + c];
  float r = sigmoidf_(ir + hr);
  float z = sigmoidf_(iz + hz);
  float n = tanhf(inn + r * hn);
  float hv = (1.0f - z) * n + z * 0.0f;
  h2[idx] = hv;
  u16 h, l;
  split_bf16(hv, h, l);
  h_hi[idx] = h; h_lo[idx] = l;
}

// ------------------------- GRU gate combine (both heads) + h split -------------------------
__global__ __launch_bounds__(256) void gru_combine_kernel(
    const float* __restrict__ gi2, const float* __restrict__ gh2, float* __restrict__ h2,
    u16* __restrict__ h_hi, u16* __restrict__ h_lo) {
  int idx = blockIdx.x * blockDim.x + threadIdx.x;
  if (idx >= 2 * BH) return;
  int e = idx / BH, rem = idx % BH;
  int b = rem / H_DIM, c = rem - b * H_DIM;
  const float* gib = gi2 + ((size_t)e * B_DIM + b) * HG;
  const float* ghb = gh2 + ((size_t)e * B_DIM + b) * HG;
  float ir = gib[c], iz = gib[H_DIM + c], inn = gib[2 * H_DIM + c];
  float hr = ghb[c], hz = ghb[H_DIM + c], hn = ghb[2 * H_DIM + c];
  float r = sigmoidf_(ir + hr);
  float z = sigmoidf_(iz + hz);
  float n = tanhf(inn + r * hn);
  float hv = (1.0f - z) * n + z * h2[idx];
  h2[idx] = hv;
  u16 h, l;
  split_bf16(hv, h, l);
  h_hi[idx] = h; h_lo[idx] = l;
}

// ------------------------- sampling (both heads) + fused cur_in update -------------------------
#define STH 256
#define PER_TH 20  // ceil(5001/256)

__global__ __launch_bounds__(STH) void sample_kernel(
    float* __restrict__ probs, const int* __restrict__ x_mask,
    int* __restrict__ indb, int j, uint4 keys,
    const float* __restrict__ cls, const float* __restrict__ ae_w,
    u16* __restrict__ cur_hi, u16* __restrict__ cur_lo, int docur) {
  int b = blockIdx.x;
  int e = blockIdx.y;
  int t = threadIdx.x;
  uint32_t k0 = (e == 0) ? keys.x : keys.z;
  uint32_t k1 = (e == 0) ? keys.y : keys.w;
  __shared__ float rv[STH];
  __shared__ int ri[STH];
  __shared__ int s_ind;

  float* prow = probs + (((size_t)b * NHEADS + e) * NSTEPS + j) * A_DIM;
  const int* mrow = x_mask + (size_t)b * A_DIM;

  int prev[3];
  bool dead = false;
  for (int tt = 0; tt < j; ++tt) {
    prev[tt] = indb[(e * NSTEPS + tt) * B_DIM + b];
    if (prev[tt] == 0) dead = true;
  }

  bool rowany = true;
  if (j == 0) {
    int any = 0;
    for (int a = t; a < A_DIM; a += STH) any |= mrow[a];
    ri[t] = any; __syncthreads();
    for (int s = STH / 2; s > 0; s >>= 1) {
      if (t < s) ri[t] |= ri[t + s];
      __syncthreads();
    }
    rowany = (ri[0] != 0);
    __syncthreads();
  }

  float v[PER_TH];
  float lmax = -3.0e38f;
#pragma unroll
  for (int s = 0; s < PER_TH; ++s) {
    int a = t + s * STH;
    float val = -3.0e38f;
    if (a < A_DIM) {
      int m;
      if (j == 0) {
        m = (a == 0) ? (rowany ? mrow[0] : 1) : mrow[a];
      } else if (a == 0) {
        m = 1;
      } else if (dead) {
        m = 0;
      } else {
        m = mrow[a];
        if (m) {
          for (int tt = 0; tt < j; ++tt)
            if (prev[tt] == a) { m = 0; break; }
        }
      }
      if (m > 0)
        val = prow[a] + gumbel_noise(k0, k1, (uint32_t)(b * A_DIM + a));
    }
    v[s] = val;
    lmax = fmaxf(lmax, val);
  }

  rv[t] = lmax; __syncthreads();
  for (int s = STH / 2; s > 0; s >>= 1) {
    if (t < s) rv[t] = fmaxf(rv[t], rv[t + s]);
    __syncthreads();
  }
  float m = rv[0]; __syncthreads();

  float lsum = 0.0f;
#pragma unroll
  for (int s = 0; s < PER_TH; ++s) {
    int a = t + s * STH;
    float ev = (a < A_DIM && v[s] > -1.0e37f) ? expf(v[s] - m) : 0.0f;
    v[s] = ev; lsum += ev;
  }
  rv[t] = lsum; __syncthreads();
  for (int s = STH / 2; s > 0; s >>= 1) {
    if (t < s) rv[t] += rv[t + s];
    __syncthreads();
  }
  float ssum = rv[0]; __syncthreads();

  float besty = -1.0f; int besti = A_DIM;
#pragma unroll
  for (int s = 0; s < PER_TH; ++s) {
    int a = t + s * STH;
    if (a < A_DIM) {
      float y = v[s] / ssum;
      if (y > besty) { besty = y; besti = a; }
    }
  }
  rv[t] = besty; ri[t] = besti; __syncthreads();
  for (int s = STH / 2; s > 0; s >>= 1) {
    if (t < s) {
      float y2 = rv[t + s]; int i2 = ri[t + s];
      if (y2 > rv[t] || (y2 == rv[t] && i2 < ri[t])) { rv[t] = y2; ri[t] = i2; }
    }
    __syncthreads();
  }
  if (t == 0) { s_ind = ri[0]; indb[(e * NSTEPS + j) * B_DIM + b] = ri[0]; }
  __syncthreads();
  int ind = s_ind;

  for (int a = t; a < A_DIM; a += STH) prow[a] = (a == ind) ? 1.0f : 0.0f;

  // fused cur_in = cls + ae_w[ind], split to bf16 hi/lo (next step's GEMM A operand)
  if (docur) {
    const float* crow = cls + (size_t)b * H_DIM;
    const float* arow = ae_w + (size_t)ind * H_DIM;
    u16* chh = cur_hi + (size_t)e * BH + (size_t)b * H_DIM;
    u16* cll = cur_lo + (size_t)e * BH + (size_t)b * H_DIM;
    for (int c = t; c < H_DIM; c += STH) {
      float vv = crow[c] + arow[c];
      u16 hh, ll;
      split_bf16(vv, hh, ll);
      chh[c] = hh; cll[c] = ll;
    }
  }
}

// ------------------------- per-head consequent estimator (both heads) -------------------------
__global__ __launch_bounds__(256) void head_final_kernel(
    const int* __restrict__ indb, const float* __restrict__ Wmu,
    const float* __restrict__ bmu, const float* __restrict__ Wcov,
    const float* __restrict__ bcov, const float* __restrict__ alpha,
    float* __restrict__ matcp) {
  int idx = blockIdx.x * blockDim.x + threadIdx.x;
  if (idx >= NHEADS * B_DIM) return;
  int e = idx / B_DIM, b = idx - e * B_DIM;
  float a0 = 0.0f, a1 = 0.0f, ac = 0.0f;
  for (int j = 0; j < NSTEPS; ++j) {
    int ind = indb[(e * NSTEPS + j) * B_DIM + b];
    a0 += 0.25f * Wmu[(size_t)ind * C_DIM + 0];
    a1 += 0.25f * Wmu[(size_t)ind * C_DIM + 1];
    ac += 0.25f * Wcov[ind];
  }
  float mu0 = sigmoidf_(a0 + bmu[0]);
  float mu1 = sigmoidf_(a1 + bmu[1]);
  float cov = sigmoidf_(ac + bcov[0]);
  float n = cov * 56000.0f;
  float sf = alpha[0] / n;
  float denom = 1.0f + 2.0f * sf;
  matcp[((size_t)b * NHEADS + e) * C_DIM + 0] = (mu0 + sf) / denom;
  matcp[((size_t)b * NHEADS + e) * C_DIM + 1] = (mu1 + sf) / denom;
}

__global__ __launch_bounds__(256) void final_out_kernel(
    const float* __restrict__ matcp, float* __restrict__ out) {
  int idx = blockIdx.x * blockDim.x + threadIdx.x;
  if (idx >= B_DIM * C_DIM) return;
  int b = idx / C_DIM, c = idx - b * C_DIM;
  float s = matcp[((size_t)b * NHEADS + 0) * C_DIM + c] +
            matcp[((size_t)b * NHEADS + 1) * C_DIM + c];
  out[idx] = logf(s * 0.5f);
}

// ------------------------- orchestration -------------------------
extern "C" void kernel_launch(void* const* d_in, const int* in_sizes, int n_in,
                              void* d_out, int out_size, void* d_ws, size_t ws_size,
                              hipStream_t stream) {
  const float* x     = (const float*)d_in[0];
  const int*   xmask = (const int*)d_in[1];
  const float* W1 = (const float*)d_in[2];  const float* b1 = (const float*)d_in[3];
  const float* W2 = (const float*)d_in[4];  const float* b2 = (const float*)d_in[5];
  const float* W3 = (const float*)d_in[6];  const float* b3 = (const float*)d_in[7];
  const float* gWih = (const float*)d_in[8];  const float* gWhh = (const float*)d_in[9];
  const float* gbih = (const float*)d_in[10]; const float* gbhh = (const float*)d_in[11];
  const float* hW = (const float*)d_in[12];   const float* hb = (const float*)d_in[13];
  const float* ae_w = (const float*)d_in[14];
  const float* Wmu  = (const float*)d_in[15]; const float* bmu  = (const float*)d_in[16];
  const float* Wcov = (const float*)d_in[17]; const float* bcov = (const float*)d_in[18];
  const float* alpha = (const float*)d_in[19];

  float* out = (float*)d_out;
  float* probs = out + (size_t)B_DIM * C_DIM;                       // [B, 2, 4, A]
  float* matcp = probs + (size_t)B_DIM * NHEADS * NSTEPS * A_DIM;   // [B, 2, C]

  uint8_t* wsp = (uint8_t*)d_ws;
  auto alloc = [&](size_t bytes) {
    uint8_t* p = wsp;
    wsp += (bytes + 255) & ~(size_t)255;
    return p;
  };
  float* cls  = (float*)alloc((size_t)BH * 4);
  float* h2   = (float*)alloc((size_t)2 * BH * 4);
  float* gi2  = (float*)alloc((size_t)2 * B_DIM * HG * 4);
  float* gh2  = (float*)alloc((size_t)2 * B_DIM * HG * 4);
  u16* h_hi   = (u16*)alloc((size_t)2 * BH * 2);
  u16* h_lo   = (u16*)alloc((size_t)2 * BH * 2);
  u16* cur_hi = (u16*)alloc((size_t)2 * BH * 2);
  u16* cur_lo = (u16*)alloc((size_t)2 * BH * 2);
  u16* WihT_h = (u16*)alloc((size_t)2 * HG * H_DIM * 2);
  u16* WihT_l = (u16*)alloc((size_t)2 * HG * H_DIM * 2);
  u16* WhhT_h = (u16*)alloc((size_t)2 * HG * H_DIM * 2);
  u16* WhhT_l = (u16*)alloc((size_t)2 * HG * H_DIM * 2);
  u16* hWT_h  = (u16*)alloc((size_t)2 * A_DIM * H_DIM * 2);
  u16* hWT_l  = (u16*)alloc((size_t)2 * A_DIM * H_DIM * 2);
  u16* x_hi   = (u16*)alloc((size_t)B_DIM * DIN * 2);
  u16* x_lo   = (u16*)alloc((size_t)B_DIM * DIN * 2);
  u16* t1_hi  = (u16*)alloc((size_t)BH * 2);
  u16* t1_lo  = (u16*)alloc((size_t)BH * 2);
  u16* t2_hi  = (u16*)alloc((size_t)BH * 2);
  u16* t2_lo  = (u16*)alloc((size_t)BH * 2);
  u16* W1T_h  = (u16*)alloc((size_t)H_DIM * DIN * 2);
  u16* W1T_l  = (u16*)alloc((size_t)H_DIM * DIN * 2);
  u16* W2T_h  = (u16*)alloc((size_t)H_DIM * H_DIM * 2);
  u16* W2T_l  = (u16*)alloc((size_t)H_DIM * H_DIM * 2);
  u16* W3T_h  = (u16*)alloc((size_t)H_DIM * H_DIM * 2);
  u16* W3T_l  = (u16*)alloc((size_t)H_DIM * H_DIM * 2);
  int* indb   = (int*)alloc((size_t)NHEADS * NSTEPS * B_DIM * 4);

  dim3 blk(256);

  // ---- one-time prep: all 9 weight transposes in one launch + x split ----
  {
    TS9 ts;
    ts.t[0] = {gWih,                    WihT_h,                    WihT_l,                    H_DIM, HG};
    ts.t[1] = {gWih + (size_t)H_DIM*HG, WihT_h + (size_t)HG*H_DIM, WihT_l + (size_t)HG*H_DIM, H_DIM, HG};
    ts.t[2] = {gWhh,                    WhhT_h,                    WhhT_l,                    H_DIM, HG};
    ts.t[3] = {gWhh + (size_t)H_DIM*HG, WhhT_h + (size_t)HG*H_DIM, WhhT_l + (size_t)HG*H_DIM, H_DIM, HG};
    ts.t[4] = {hW,                          hWT_h,                           hWT_l,                           H_DIM, A_DIM};
    ts.t[5] = {hW + (size_t)H_DIM*A_DIM,    hWT_h + (size_t)A_DIM*H_DIM,     hWT_l + (size_t)A_DIM*H_DIM,     H_DIM, A_DIM};
    ts.t[6] = {W1, W1T_h, W1T_l, DIN,   H_DIM};
    ts.t[7] = {W2, W2T_h, W2T_l, H_DIM, H_DIM};
    ts.t[8] = {W3, W3T_h, W3T_l, H_DIM, H_DIM};
    transpose_split_b<<<dim3((A_DIM + 31) / 32, H_DIM / 32, 9), blk, 0, stream>>>(ts);
  }
  split_kernel<<<(B_DIM * DIN + 255) / 256, blk, 0, stream>>>(x, x_hi, x_lo, B_DIM * DIN);

  auto setE = [](GemmS& g, int e, const u16* ah, const u16* al, const u16* bhp, const u16* blp,
                 const float* bias, float* Cf, u16* chp, u16* clp,
                 int N, int nbx, long long ldc, int act, int dup) {
    g.Ah[e] = ah; g.Al[e] = al; g.Bh[e] = bhp; g.Bl[e] = blp;
    g.bias[e] = bias; g.C[e] = Cf; g.Ch[e] = chp; g.Cl[e] = clp;
    g.N[e] = N; g.nbx[e] = nbx; g.ldc[e] = ldc; g.act[e] = act; g.dup[e] = dup;
  };

  const int NBX_M = H_DIM / 64;           // 12 (MLP)
  const int NBX_G = HG / 64;              // 36 (gates)
  const int NBX_L = (A_DIM + 63) / 64;    // 79 (logits)

  // ---- MLP via bf16x3 MFMA, fused bias/relu/split epilogues; MLP3 also fuses cur=cls init ----
  {
    GemmS g{};
    setE(g, 0, x_hi, x_lo, W1T_h, W1T_l, b1, nullptr, t1_hi, t1_lo, H_DIM, NBX_M, H_DIM, 1, 0);
    gemm_mfma<<<dim3(NBX_M * 8, 1), blk, 0, stream>>>(g, DIN, 8);
  }
  {
    GemmS g{};
    setE(g, 0, t1_hi, t1_lo, W2T_h, W2T_l, b2, nullptr, t2_hi, t2_lo, H_DIM, NBX_M, H_DIM, 1, 0);
    gemm_mfma<<<dim3(NBX_M * 8, 1), blk, 0, stream>>>(g, H_DIM, 8);
  }
  {
    GemmS g{};
    // writes cls (f32) AND cur_hi/lo for head0 (+dup to head1) — replaces init_state
    setE(g, 0, t2_hi, t2_lo, W3T_h, W3T_l, b3, cls, cur_hi, cur_lo, H_DIM, NBX_M, H_DIM, 0, 1);
    gemm_mfma<<<dim3(NBX_M * 8, 1), blk, 0, stream>>>(g, H_DIM, 8);
  }

  // host-side key schedule: key(42) -> fold_in(head) -> fold_in(step)
  uint32_t bk0 = 0u, bk1 = 42u;
  uint32_t hk[2][2];
  threefry2x32(bk0, bk1, 0u, 0u, hk[0][0], hk[0][1]);
  threefry2x32(bk0, bk1, 0u, 1u, hk[1][0], hk[1][1]);

  for (int j = 0; j < NSTEPS; ++j) {
    // ---- gates GEMM: j=0 -> z=2 (gi only; gh==bhh); else z=4 {h0:gi, h0:gh, h1:gi, h1:gh} ----
    if (j == 0) {
      GemmS g{};
      for (int head = 0; head < NHEADS; ++head)
        setE(g, head, cur_hi + (size_t)head * BH, cur_lo + (size_t)head * BH,
             WihT_h + (size_t)head * HG * H_DIM, WihT_l + (size_t)head * HG * H_DIM,
             gbih + (size_t)head * HG, gi2 + (size_t)head * B_DIM * HG, nullptr, nullptr,
             HG, NBX_G, HG, 0, 0);
      gemm_mfma<<<dim3(NBX_G * 8, 2), blk, 0, stream>>>(g, H_DIM, 8);
      gru_combine_first<<<(2 * BH + 255) / 256, blk, 0, stream>>>(gi2, gbhh, h2, h_hi, h_lo);
    } else {
      GemmS g{};
      for (int head = 0; head < NHEADS; ++head) {
        setE(g, head * 2 + 0, cur_hi + (size_t)head * BH, cur_lo + (size_t)head * BH,
             WihT_h + (size_t)head * HG * H_DIM, WihT_l + (size_t)head * HG * H_DIM,
             gbih + (size_t)head * HG, gi2 + (size_t)head * B_DIM * HG, nullptr, nullptr,
             HG, NBX_G, HG, 0, 0);
        setE(g, head * 2 + 1, h_hi + (size_t)head * BH, h_lo + (size_t)head * BH,
             WhhT_h + (size_t)head * HG * H_DIM, WhhT_l + (size_t)head * HG * H_DIM,
             gbhh + (size_t)head * HG, gh2 + (size_t)head * B_DIM * HG, nullptr, nullptr,
             HG, NBX_G, HG, 0, 0);
      }
      gemm_mfma<<<dim3(NBX_G * 8, 4), blk, 0, stream>>>(g, H_DIM, 8);
      gru_combine_kernel<<<(2 * BH + 255) / 256, blk, 0, stream>>>(gi2, gh2, h2, h_hi, h_lo);
    }

    // ---- logits GEMM z=2: N=5001, C into probs rows ----
    {
      GemmS g{};
      for (int head = 0; head < NHEADS; ++head)
        setE(g, head, h_hi + (size_t)head * BH, h_lo + (size_t)head * BH,
             hWT_h + (size_t)head * A_DIM * H_DIM, hWT_l + (size_t)head * A_DIM * H_DIM,
             hb + (size_t)head * A_DIM, probs + (size_t)(head * NSTEPS + j) * A_DIM,
             nullptr, nullptr, A_DIM, NBX_L, (long long)NHEADS * NSTEPS * A_DIM, 0, 0);
      gemm_mfma<<<dim3(NBX_L * 8, 2), blk, 0, stream>>>(g, H_DIM, 8);
    }

    // ---- sample + fused cur update ----
    uint32_t s00, s01, s10, s11;
    threefry2x32(hk[0][0], hk[0][1], 0u, (uint32_t)j, s00, s01);
    threefry2x32(hk[1][0], hk[1][1], 0u, (uint32_t)j, s10, s11);
    uint4 keys; keys.x = s00; keys.y = s01; keys.z = s10; keys.w = s11;
    sample_kernel<<<dim3(B_DIM, NHEADS), dim3(STH), 0, stream>>>(
        probs, xmask, indb, j, keys, cls, ae_w, cur_hi, cur_lo, (j < NSTEPS - 1) ? 1 : 0);
  }

  head_final_kernel<<<(NHEADS * B_DIM + 255) / 256, blk, 0, stream>>>(
      indb, Wmu, bmu, Wcov, bcov, alpha, matcp);
  final_out_kernel<<<(B_DIM * C_DIM + 255) / 256, blk, 0, stream>>>(matcp, out);
}

// Round 11
// 822.962 us; speedup vs baseline: 1.1430x; 1.0499x over previous
//
#include <hip/hip_runtime.h>
#include <hip/hip_bf16.h>
#include <stdint.h>
#include <stddef.h>

#define B_DIM   1024
#define DIN     512
#define H_DIM   768
#define A_DIM   5001
#define NHEADS  2
#define NSTEPS  4
#define C_DIM   2
#define NEG_VAL -1e30f
#define BH      (B_DIM * H_DIM)
#define HG      (3 * H_DIM)

typedef unsigned short u16;
typedef __attribute__((ext_vector_type(8))) short v8s;
typedef __attribute__((ext_vector_type(4))) float v4f;

typedef const __attribute__((address_space(1))) uint32_t* gas_ptr;
typedef __attribute__((address_space(3))) uint32_t* las_ptr;

__device__ __forceinline__ void load_lds16(const void* g, void* l) {
  // async global->LDS DMA, 16B per lane; LDS dest is wave-uniform base + lane*16
  __builtin_amdgcn_global_load_lds((gas_ptr)g, (las_ptr)l, 16, 0, 0);
}

// ------------------------- Threefry-2x32 (JAX-compatible) -------------------------
__host__ __device__ inline uint32_t rotl32(uint32_t x, int d) {
  return (x << d) | (x >> (32 - d));
}

__host__ __device__ inline void threefry2x32(uint32_t k0, uint32_t k1,
                                             uint32_t x0, uint32_t x1,
                                             uint32_t& o0, uint32_t& o1) {
  uint32_t ks2 = k0 ^ k1 ^ 0x1BD11BDAu;
  x0 += k0; x1 += k1;
#define TFR(d) { x0 += x1; x1 = rotl32(x1, (d)); x1 ^= x0; }
  TFR(13) TFR(15) TFR(26) TFR(6)  x0 += k1;  x1 += ks2 + 1u;
  TFR(17) TFR(29) TFR(16) TFR(24) x0 += ks2; x1 += k0 + 2u;
  TFR(13) TFR(15) TFR(26) TFR(6)  x0 += k0;  x1 += k1 + 3u;
  TFR(17) TFR(29) TFR(16) TFR(24) x0 += k1;  x1 += ks2 + 4u;
  TFR(13) TFR(15) TFR(26) TFR(6)  x0 += ks2; x1 += k0 + 5u;
#undef TFR
  o0 = x0; o1 = x1;
}

__device__ inline float gumbel_noise(uint32_t k0, uint32_t k1, uint32_t idx) {
  uint32_t o0, o1;
  threefry2x32(k0, k1, 0u, idx, o0, o1);
  uint32_t bits = o0 ^ o1;
  float f = __uint_as_float(0x3f800000u | (bits >> 9)) - 1.0f;   // [0,1)
  float u = fmaxf(1e-9f, f * (1.0f - 1e-9f) + 1e-9f);            // jax.random.uniform
  return -logf(-logf(u));                                        // Gumbel(0,1)
}

// XLA logistic lowering: 0.5 + 0.5 * tanh(0.5 * x)
__device__ inline float sigmoidf_(float x) { return 0.5f * tanhf(0.5f * x) + 0.5f; }

__device__ inline void split_bf16(float x, u16& hi, u16& lo) {
  __hip_bfloat16 h = __float2bfloat16(x);
  float hf = __bfloat162float(h);
  __hip_bfloat16 l = __float2bfloat16(x - hf);
  hi = *(const u16*)&h;
  lo = *(const u16*)&l;
}

// ------------------------- fp32 split-K GEMM (MLP): 64x64 tile, K-chunk per grid.z -------------------------
__global__ __launch_bounds__(256) void gemm_splitk(
    const float* __restrict__ A, const float* __restrict__ B,
    float* __restrict__ part, int M, int N, int K, int kchunk) {
  __shared__ float As[16][65];
  __shared__ float Bs[16][64];
  int tid = threadIdx.x;
  int bm = blockIdx.y * 64, bn = blockIdx.x * 64;
  const int s = blockIdx.z;
  const int kb = s * kchunk;
  const int ke = (kb + kchunk < K) ? (kb + kchunk) : K;
  int tx = tid & 15, ty = tid >> 4;
  float acc[4][4] = {};
  for (int k0 = kb; k0 < ke; k0 += 16) {
#pragma unroll
    for (int r = 0; r < 4; ++r) {
      int m = (tid >> 4) + r * 16;
      int k = tid & 15;
      As[k][m] = A[(size_t)(bm + m) * K + k0 + k];
    }
#pragma unroll
    for (int r = 0; r < 4; ++r) {
      int n = tid & 63;
      int k = (tid >> 6) + r * 4;
      int gn = bn + n;
      Bs[k][n] = (gn < N) ? B[(size_t)(k0 + k) * N + gn] : 0.0f;
    }
    __syncthreads();
#pragma unroll
    for (int kk = 0; kk < 16; ++kk) {
      float a[4], bb[4];
#pragma unroll
      for (int i = 0; i < 4; ++i) a[i] = As[kk][ty * 4 + i];
#pragma unroll
      for (int jj = 0; jj < 4; ++jj) bb[jj] = Bs[kk][tx * 4 + jj];
#pragma unroll
      for (int i = 0; i < 4; ++i)
#pragma unroll
        for (int jj = 0; jj < 4; ++jj) acc[i][jj] = fmaf(a[i], bb[jj], acc[i][jj]);
    }
    __syncthreads();
  }
  float* po = part + (size_t)s * M * N;
#pragma unroll
  for (int i = 0; i < 4; ++i) {
    int m = bm + ty * 4 + i;
#pragma unroll
    for (int jj = 0; jj < 4; ++jj) {
      int n = bn + tx * 4 + jj;
      if (n < N) po[(size_t)m * N + n] = acc[i][jj];
    }
  }
}

__global__ __launch_bounds__(256) void reduce_bias_act(
    const float* __restrict__ part, const float* __restrict__ bias,
    float* __restrict__ C, int M, int N, int S, int act) {
  int idx = blockIdx.x * blockDim.x + threadIdx.x;
  if (idx >= M * N) return;
  int n = idx % N;
  float v = 0.0f;
  for (int s = 0; s < S; ++s) v += part[(size_t)s * M * N + idx];
  v += bias[n];
  if (act == 1) v = fmaxf(v, 0.0f);
  C[idx] = v;
}

// ------------------------- batched weight transpose + bf16 split: W[K][N] -> hi/lo[N][K] -------------------------
struct TS { const float* W; u16* hi; u16* lo; int K; int N; };
struct TS6 { TS t[6]; };

__global__ __launch_bounds__(256) void transpose_split_b(TS6 ts) {
  const TS p = ts.t[blockIdx.z];
  const int k0 = blockIdx.y * 32, n0 = blockIdx.x * 32;
  if (k0 >= p.K || n0 >= p.N) return;
  __shared__ float tile[32][33];
  const int tx = threadIdx.x & 31, ty = threadIdx.x >> 5;
#pragma unroll
  for (int r = ty; r < 32; r += 8) {
    int n = n0 + tx;
    tile[r][tx] = (n < p.N) ? p.W[(size_t)(k0 + r) * p.N + n] : 0.0f;
  }
  __syncthreads();
#pragma unroll
  for (int r = ty; r < 32; r += 8) {
    int n = n0 + r, k = k0 + tx;
    if (n < p.N) {
      u16 h, l;
      split_bf16(tile[tx][r], h, l);
      p.hi[(size_t)n * p.K + k] = h;
      p.lo[(size_t)n * p.K + k] = l;
    }
  }
}

// ------------------------- bf16x3 MFMA GEMM: 128x128 tile, 4 waves, BK=32 (833-measured core) -------------------------
// Staging via global_load_lds (16B/lane DMA). LDS layout linear [row][32 u16];
// XOR swizzle slot^((row>>1)&3) applied on the GLOBAL source and on the ds_read side.
struct GemmS {
  const u16* Ah[4]; const u16* Al[4];
  const u16* Bh[4]; const u16* Bl[4];
  const float* bias[4]; float* C[4];
};

__global__ __launch_bounds__(256, 2) void gemm_mfma(
    GemmS gs, int K, int N, int Nclamp, long long ldc, int nbx, int nby) {
  const int e = blockIdx.y;
  // XCD-chunked, m-fastest block ordering (nbx*nby divisible by 8)
  const int nwg = nbx * nby;
  const int chunk = nwg >> 3;
  const int orig = blockIdx.x;
  const int lid = (orig & 7) * chunk + (orig >> 3);
  const int by = lid % nby;
  const int bx = lid / nby;
  const int bm = by * 128, bn = bx * 128;

  __shared__ __align__(16) u16 lds[4][128 * 32];  // Ahi, Alo, Bhi, Blo (8KB each)

  const int tid = threadIdx.x;
  const int wv = tid >> 6, ln = tid & 63;
  const int wr = wv >> 1, wc = wv & 1;     // wave 2x2 grid for compute
  const int lk = ln >> 4;                  // k-group 0..3
  const int lm = ln & 15;                  // frag row/col
  const int fswz = (lm >> 1) & 3;          // read-side XOR swizzle

  // staging: wave wv DMAs tensor wv; per issue i rows i*16+(ln>>2)
  const int lrow = ln >> 2;                          // 0..15
  const int slot = (ln & 3) ^ ((lrow >> 1) & 3);     // issue-invariant source swizzle
  const u16* tsrc = (wv == 0) ? gs.Ah[e] : (wv == 1) ? gs.Al[e]
                  : (wv == 2) ? gs.Bh[e] : gs.Bl[e];
  const int isB = (wv >= 2);
  const int rowbase = isB ? bn : bm;

  const float* bias = gs.bias[e];
  float* C = gs.C[e];

  v4f acc[4][4];
#pragma unroll
  for (int i = 0; i < 4; ++i)
#pragma unroll
    for (int j = 0; j < 4; ++j) acc[i][j] = (v4f){0.f, 0.f, 0.f, 0.f};

  for (int k0 = 0; k0 < K; k0 += 32) {
#pragma unroll
    for (int i = 0; i < 8; ++i) {
      int gr = rowbase + i * 16 + lrow;
      if (isB && gr >= Nclamp) gr = Nclamp - 1;      // OOB N rows: duplicate last (C-write guarded)
      const u16* gp = tsrc + (size_t)gr * K + k0 + slot * 8;
      load_lds16(gp, (void*)&lds[wv][i * 512]);
    }
    __syncthreads();   // compiler drains vmcnt(0) before barrier (m97 pattern)

    v8s ah[4], al[4], bh[4], bl[4];
#pragma unroll
    for (int mi = 0; mi < 4; ++mi) {
      const int r = wr * 64 + mi * 16 + lm;
      const int off = r * 32 + ((lk ^ fswz) * 8);
      ah[mi] = *(const v8s*)&lds[0][off];
      al[mi] = *(const v8s*)&lds[1][off];
    }
#pragma unroll
    for (int ni = 0; ni < 4; ++ni) {
      const int r = wc * 64 + ni * 16 + lm;
      const int off = r * 32 + ((lk ^ fswz) * 8);
      bh[ni] = *(const v8s*)&lds[2][off];
      bl[ni] = *(const v8s*)&lds[3][off];
    }
    // 3-term split product
#pragma unroll
    for (int mi = 0; mi < 4; ++mi)
#pragma unroll
      for (int ni = 0; ni < 4; ++ni)
        acc[mi][ni] = __builtin_amdgcn_mfma_f32_16x16x32_bf16(ah[mi], bh[ni], acc[mi][ni], 0, 0, 0);
#pragma unroll
    for (int mi = 0; mi < 4; ++mi)
#pragma unroll
      for (int ni = 0; ni < 4; ++ni)
        acc[mi][ni] = __builtin_amdgcn_mfma_f32_16x16x32_bf16(ah[mi], bl[ni], acc[mi][ni], 0, 0, 0);
#pragma unroll
    for (int mi = 0; mi < 4; ++mi)
#pragma unroll
      for (int ni = 0; ni < 4; ++ni)
        acc[mi][ni] = __builtin_amdgcn_mfma_f32_16x16x32_bf16(al[mi], bh[ni], acc[mi][ni], 0, 0, 0);

    __syncthreads();   // protect LDS before next tile's DMA
  }

  // epilogue: C/D layout col=lane&15, row=(lane>>4)*4+reg (m89-verified)
#pragma unroll
  for (int mi = 0; mi < 4; ++mi) {
    const int m = bm + wr * 64 + mi * 16 + lk * 4;
#pragma unroll
    for (int ni = 0; ni < 4; ++ni) {
      const int n = bn + wc * 64 + ni * 16 + lm;
      if (n < N) {
        const float bv = bias[n];
        float* cp = C + (size_t)m * ldc + n;
#pragma unroll
        for (int r = 0; r < 4; ++r)
          cp[(size_t)r * ldc] = acc[mi][ni][r] + bv;
      }
    }
  }
}

// ------------------------- init: cur = cls (split, both heads) -------------------------
__global__ __launch_bounds__(256) void init_state_kernel(
    const float* __restrict__ cls,
    u16* __restrict__ cur_hi, u16* __restrict__ cur_lo) {
  int idx = blockIdx.x * blockDim.x + threadIdx.x;
  if (idx >= 2 * BH) return;
  int rem = idx % BH;
  u16 h, l;
  split_bf16(cls[rem], h, l);
  cur_hi[idx] = h; cur_lo[idx] = l;
}

// ------------------------- GRU combine, j=0: gh == bhh exactly (h=0) -------------------------
__global__ __launch_bounds__(256) void gru_combine_first(
    const float* __restrict__ gi2, const float* __restrict__ gbhh, float* __restrict__ h2,
    u16* __restrict__ h_hi, u16* __restrict__ h_lo) {
  int idx = blockIdx.x * blockDim.x + threadIdx.x;
  if (idx >= 2 * BH) return;
  int e = idx / BH, rem = idx % BH;
  int b = rem / H_DIM, c = rem - b * H_DIM;
  const float* gib = gi2 + ((size_t)e * B_DIM + b) * HG;
  const float* bb = gbhh + (size_t)e * HG;
  float ir = gib[c], iz = gib[H_DIM + c], inn = gib[2 * H_DIM + c];
  float hr = bb[c], hz = bb[H_DIM + c], hn = bb[2 * H_DIM + c];
  float r = sigmoidf_(ir + hr);
  float z = sigmoidf_(iz + hz);
  float n = tanhf(inn + r * hn);
  float hv = (1.0f - z) * n + z * 0.0f;
  h2[idx] = hv;
  u16 h, l;
  split_bf16(hv, h, l);
  h_hi[idx] = h; h_lo[idx] = l;
}

// ------------------------- GRU gate combine (both heads) + h split -------------------------
__global__ __launch_bounds__(256) void gru_combine_kernel(
    const float* __restrict__ gi2, const float* __restrict__ gh2, float* __restrict__ h2,
    u16* __restrict__ h_hi, u16* __restrict__ h_lo) {
  int idx = blockIdx.x * blockDim.x + threadIdx.x;
  if (idx >= 2 * BH) return;
  int e = idx / BH, rem = idx % BH;
  int b = rem / H_DIM, c = rem - b * H_DIM;
  const float* gib = gi2 + ((size_t)e * B_DIM + b) * HG;
  const float* ghb = gh2 + ((size_t)e * B_DIM + b) * HG;
  float ir = gib[c], iz = gib[H_DIM + c], inn = gib[2 * H_DIM + c];
  float hr = ghb[c], hz = ghb[H_DIM + c], hn = ghb[2 * H_DIM + c];
  float r = sigmoidf_(ir + hr);
  float z = sigmoidf_(iz + hz);
  float n = tanhf(inn + r * hn);
  float hv = (1.0f - z) * n + z * h2[idx];
  h2[idx] = hv;
  u16 h, l;
  split_bf16(hv, h, l);
  h_hi[idx] = h; h_lo[idx] = l;
}

// ------------------------- sampling (both heads), in-place on probs rows + fused cur_in -------------------------
#define STH 256
#define PER_TH 20  // ceil(5001/256)

__global__ __launch_bounds__(STH) void sample_kernel(
    float* __restrict__ probs, const int* __restrict__ x_mask,
    int* __restrict__ indb, int j, uint4 keys,
    const float* __restrict__ cls, const float* __restrict__ ae_w,
    u16* __restrict__ cur_hi, u16* __restrict__ cur_lo, int docur) {
  int b = blockIdx.x;
  int e = blockIdx.y;
  int t = threadIdx.x;
  uint32_t k0 = (e == 0) ? keys.x : keys.z;
  uint32_t k1 = (e == 0) ? keys.y : keys.w;
  __shared__ float rv[STH];
  __shared__ int ri[STH];
  __shared__ int s_ind;

  float* prow = probs + (((size_t)b * NHEADS + e) * NSTEPS + j) * A_DIM;
  const int* mrow = x_mask + (size_t)b * A_DIM;

  int prev[3];
  bool dead = false;
  for (int tt = 0; tt < j; ++tt) {
    prev[tt] = indb[(e * NSTEPS + tt) * B_DIM + b];
    if (prev[tt] == 0) dead = true;
  }

  bool rowany = true;
  if (j == 0) {
    int any = 0;
    for (int a = t; a < A_DIM; a += STH) any |= mrow[a];
    ri[t] = any; __syncthreads();
    for (int s = STH / 2; s > 0; s >>= 1) {
      if (t < s) ri[t] |= ri[t + s];
      __syncthreads();
    }
    rowany = (ri[0] != 0);
    __syncthreads();
  }

  float v[PER_TH];
  float lmax = -3.0e38f;
#pragma unroll
  for (int s = 0; s < PER_TH; ++s) {
    int a = t + s * STH;
    float val = -3.0e38f;
    if (a < A_DIM) {
      int m;
      if (j == 0) {
        m = (a == 0) ? (rowany ? mrow[0] : 1) : mrow[a];
      } else if (a == 0) {
        m = 1;
      } else if (dead) {
        m = 0;
      } else {
        m = mrow[a];
        if (m) {
          for (int tt = 0; tt < j; ++tt)
            if (prev[tt] == a) { m = 0; break; }
        }
      }
      if (m > 0)
        val = prow[a] + gumbel_noise(k0, k1, (uint32_t)(b * A_DIM + a));
    }
    v[s] = val;
    lmax = fmaxf(lmax, val);
  }

  rv[t] = lmax; __syncthreads();
  for (int s = STH / 2; s > 0; s >>= 1) {
    if (t < s) rv[t] = fmaxf(rv[t], rv[t + s]);
    __syncthreads();
  }
  float m = rv[0]; __syncthreads();

  float lsum = 0.0f;
#pragma unroll
  for (int s = 0; s < PER_TH; ++s) {
    int a = t + s * STH;
    float ev = (a < A_DIM && v[s] > -1.0e37f) ? expf(v[s] - m) : 0.0f;
    v[s] = ev; lsum += ev;
  }
  rv[t] = lsum; __syncthreads();
  for (int s = STH / 2; s > 0; s >>= 1) {
    if (t < s) rv[t] += rv[t + s];
    __syncthreads();
  }
  float ssum = rv[0]; __syncthreads();

  float besty = -1.0f; int besti = A_DIM;
#pragma unroll
  for (int s = 0; s < PER_TH; ++s) {
    int a = t + s * STH;
    if (a < A_DIM) {
      float y = v[s] / ssum;
      if (y > besty) { besty = y; besti = a; }
    }
  }
  rv[t] = besty; ri[t] = besti; __syncthreads();
  for (int s = STH / 2; s > 0; s >>= 1) {
    if (t < s) {
      float y2 = rv[t + s]; int i2 = ri[t + s];
      if (y2 > rv[t] || (y2 == rv[t] && i2 < ri[t])) { rv[t] = y2; ri[t] = i2; }
    }
    __syncthreads();
  }
  if (t == 0) { s_ind = ri[0]; indb[(e * NSTEPS + j) * B_DIM + b] = ri[0]; }
  __syncthreads();
  int ind = s_ind;

  for (int a = t; a < A_DIM; a += STH) prow[a] = (a == ind) ? 1.0f : 0.0f;

  // fused cur_in = cls + ae_w[ind], split to bf16 hi/lo (next step's GEMM A operand)
  if (docur) {
    const float* crow = cls + (size_t)b * H_DIM;
    const float* arow = ae_w + (size_t)ind * H_DIM;
    u16* chh = cur_hi + (size_t)e * BH + (size_t)b * H_DIM;
    u16* cll = cur_lo + (size_t)e * BH + (size_t)b * H_DIM;
    for (int c = t; c < H_DIM; c += STH) {
      float vv = crow[c] + arow[c];
      u16 hh, ll;
      split_bf16(vv, hh, ll);
      chh[c] = hh; cll[c] = ll;
    }
  }
}

// ------------------------- per-head consequent estimator (both heads) -------------------------
__global__ __launch_bounds__(256) void head_final_kernel(
    const int* __restrict__ indb, const float* __restrict__ Wmu,
    const float* __restrict__ bmu, const float* __restrict__ Wcov,
    const float* __restrict__ bcov, const float* __restrict__ alpha,
    float* __restrict__ matcp) {
  int idx = blockIdx.x * blockDim.x + threadIdx.x;
  if (idx >= NHEADS * B_DIM) return;
  int e = idx / B_DIM, b = idx - e * B_DIM;
  float a0 = 0.0f, a1 = 0.0f, ac = 0.0f;
  for (int j = 0; j < NSTEPS; ++j) {
    int ind = indb[(e * NSTEPS + j) * B_DIM + b];
    a0 += 0.25f * Wmu[(size_t)ind * C_DIM + 0];
    a1 += 0.25f * Wmu[(size_t)ind * C_DIM + 1];
    ac += 0.25f * Wcov[ind];
  }
  float mu0 = sigmoidf_(a0 + bmu[0]);
  float mu1 = sigmoidf_(a1 + bmu[1]);
  float cov = sigmoidf_(ac + bcov[0]);
  float n = cov * 56000.0f;
  float sf = alpha[0] / n;
  float denom = 1.0f + 2.0f * sf;
  matcp[((size_t)b * NHEADS + e) * C_DIM + 0] = (mu0 + sf) / denom;
  matcp[((size_t)b * NHEADS + e) * C_DIM + 1] = (mu1 + sf) / denom;
}

__global__ __launch_bounds__(256) void final_out_kernel(
    const float* __restrict__ matcp, float* __restrict__ out) {
  int idx = blockIdx.x * blockDim.x + threadIdx.x;
  if (idx >= B_DIM * C_DIM) return;
  int b = idx / C_DIM, c = idx - b * C_DIM;
  float s = matcp[((size_t)b * NHEADS + 0) * C_DIM + c] +
            matcp[((size_t)b * NHEADS + 1) * C_DIM + c];
  out[idx] = logf(s * 0.5f);
}

// ------------------------- orchestration -------------------------
extern "C" void kernel_launch(void* const* d_in, const int* in_sizes, int n_in,
                              void* d_out, int out_size, void* d_ws, size_t ws_size,
                              hipStream_t stream) {
  const float* x     = (const float*)d_in[0];
  const int*   xmask = (const int*)d_in[1];
  const float* W1 = (const float*)d_in[2];  const float* b1 = (const float*)d_in[3];
  const float* W2 = (const float*)d_in[4];  const float* b2 = (const float*)d_in[5];
  const float* W3 = (const float*)d_in[6];  const float* b3 = (const float*)d_in[7];
  const float* gWih = (const float*)d_in[8];  const float* gWhh = (const float*)d_in[9];
  const float* gbih = (const float*)d_in[10]; const float* gbhh = (const float*)d_in[11];
  const float* hW = (const float*)d_in[12];   const float* hb = (const float*)d_in[13];
  const float* ae_w = (const float*)d_in[14];
  const float* Wmu  = (const float*)d_in[15]; const float* bmu  = (const float*)d_in[16];
  const float* Wcov = (const float*)d_in[17]; const float* bcov = (const float*)d_in[18];
  const float* alpha = (const float*)d_in[19];

  float* out = (float*)d_out;
  float* probs = out + (size_t)B_DIM * C_DIM;                       // [B, 2, 4, A]
  float* matcp = probs + (size_t)B_DIM * NHEADS * NSTEPS * A_DIM;   // [B, 2, C]

  uint8_t* wsp = (uint8_t*)d_ws;
  auto alloc = [&](size_t bytes) {
    uint8_t* p = wsp;
    wsp += (bytes + 255) & ~(size_t)255;
    return p;
  };
  float* cls  = (float*)alloc((size_t)BH * 4);
  float* h2   = (float*)alloc((size_t)2 * BH * 4);
  float* gi2  = (float*)alloc((size_t)2 * B_DIM * HG * 4);
  float* gh2  = (float*)alloc((size_t)2 * B_DIM * HG * 4);   // also: MLP split-K partials (6*BH floats)
  u16* h_hi   = (u16*)alloc((size_t)2 * BH * 2);
  u16* h_lo   = (u16*)alloc((size_t)2 * BH * 2);
  u16* cur_hi = (u16*)alloc((size_t)2 * BH * 2);
  u16* cur_lo = (u16*)alloc((size_t)2 * BH * 2);
  u16* WihT_h = (u16*)alloc((size_t)2 * HG * H_DIM * 2);
  u16* WihT_l = (u16*)alloc((size_t)2 * HG * H_DIM * 2);
  u16* WhhT_h = (u16*)alloc((size_t)2 * HG * H_DIM * 2);
  u16* WhhT_l = (u16*)alloc((size_t)2 * HG * H_DIM * 2);
  u16* hWT_h  = (u16*)alloc((size_t)2 * A_DIM * H_DIM * 2);
  u16* hWT_l  = (u16*)alloc((size_t)2 * A_DIM * H_DIM * 2);
  int* indb   = (int*)alloc((size_t)NHEADS * NSTEPS * B_DIM * 4);
  float* parts = gh2;         // 6*BH floats == 2*B*HG floats exactly
  float* t1 = gi2;            // MLP temps (gi2 free pre-loop)
  float* t2 = gi2 + BH;

  dim3 blk(256);

  // ---- one-time prep: 6 weight transposes batched into one launch ----
  {
    TS6 ts;
    ts.t[0] = {gWih,                    WihT_h,                    WihT_l,                    H_DIM, HG};
    ts.t[1] = {gWih + (size_t)H_DIM*HG, WihT_h + (size_t)HG*H_DIM, WihT_l + (size_t)HG*H_DIM, H_DIM, HG};
    ts.t[2] = {gWhh,                    WhhT_h,                    WhhT_l,                    H_DIM, HG};
    ts.t[3] = {gWhh + (size_t)H_DIM*HG, WhhT_h + (size_t)HG*H_DIM, WhhT_l + (size_t)HG*H_DIM, H_DIM, HG};
    ts.t[4] = {hW,                       hWT_h,                        hWT_l,                        H_DIM, A_DIM};
    ts.t[5] = {hW + (size_t)H_DIM*A_DIM, hWT_h + (size_t)A_DIM*H_DIM,  hWT_l + (size_t)A_DIM*H_DIM,  H_DIM, A_DIM};
    transpose_split_b<<<dim3((A_DIM + 31) / 32, H_DIM / 32, 6), blk, 0, stream>>>(ts);
  }

  // ---- MLP (fp32 exact, split-K; 833-measured config): cls = (relu(relu(x@W1+b1)@W2+b2))@W3 + b3 ----
  const int MN = B_DIM * H_DIM;
  gemm_splitk<<<dim3(H_DIM / 64, B_DIM / 64, 4), blk, 0, stream>>>(
      x, W1, parts, B_DIM, H_DIM, DIN, 128);
  reduce_bias_act<<<(MN + 255) / 256, blk, 0, stream>>>(parts, b1, t1, B_DIM, H_DIM, 4, 1);
  gemm_splitk<<<dim3(H_DIM / 64, B_DIM / 64, 6), blk, 0, stream>>>(
      t1, W2, parts, B_DIM, H_DIM, H_DIM, 128);
  reduce_bias_act<<<(MN + 255) / 256, blk, 0, stream>>>(parts, b2, t2, B_DIM, H_DIM, 6, 1);
  gemm_splitk<<<dim3(H_DIM / 64, B_DIM / 64, 6), blk, 0, stream>>>(
      t2, W3, parts, B_DIM, H_DIM, H_DIM, 128);
  reduce_bias_act<<<(MN + 255) / 256, blk, 0, stream>>>(parts, b3, cls, B_DIM, H_DIM, 6, 0);

  init_state_kernel<<<(2 * BH + 255) / 256, blk, 0, stream>>>(cls, cur_hi, cur_lo);

  // host-side key schedule: key(42) -> fold_in(head) -> fold_in(step)
  uint32_t bk0 = 0u, bk1 = 42u;
  uint32_t hk[2][2];
  threefry2x32(bk0, bk1, 0u, 0u, hk[0][0], hk[0][1]);
  threefry2x32(bk0, bk1, 0u, 1u, hk[1][0], hk[1][1]);

  for (int j = 0; j < NSTEPS; ++j) {
    if (j == 0) {
      // h == 0  =>  gh == bhh exactly; only the gi GEMMs are needed (z=2)
      GemmS gb;
      for (int head = 0; head < NHEADS; ++head) {
        gb.Ah[head] = cur_hi + (size_t)head * BH;
        gb.Al[head] = cur_lo + (size_t)head * BH;
        gb.Bh[head] = WihT_h + (size_t)head * HG * H_DIM;
        gb.Bl[head] = WihT_l + (size_t)head * HG * H_DIM;
        gb.bias[head] = gbih + (size_t)head * HG;
        gb.C[head] = gi2 + (size_t)head * B_DIM * HG;
        gb.Ah[head + 2] = gb.Ah[head]; gb.Al[head + 2] = gb.Al[head];
        gb.Bh[head + 2] = gb.Bh[head]; gb.Bl[head + 2] = gb.Bl[head];
        gb.bias[head + 2] = gb.bias[head]; gb.C[head + 2] = gb.C[head];
      }
      gemm_mfma<<<dim3((HG / 128) * (B_DIM / 128), 2), blk, 0, stream>>>(
          gb, H_DIM, HG, HG, (long long)HG, HG / 128, B_DIM / 128);
      gru_combine_first<<<(2 * BH + 255) / 256, blk, 0, stream>>>(gi2, gbhh, h2, h_hi, h_lo);
    } else {
      // gates GEMM, z=4: {h0:gi, h0:gh, h1:gi, h1:gh}
      GemmS gb;
      for (int head = 0; head < NHEADS; ++head) {
        gb.Ah[head * 2 + 0] = cur_hi + (size_t)head * BH;
        gb.Al[head * 2 + 0] = cur_lo + (size_t)head * BH;
        gb.Bh[head * 2 + 0] = WihT_h + (size_t)head * HG * H_DIM;
        gb.Bl[head * 2 + 0] = WihT_l + (size_t)head * HG * H_DIM;
        gb.bias[head * 2 + 0] = gbih + (size_t)head * HG;
        gb.C[head * 2 + 0] = gi2 + (size_t)head * B_DIM * HG;
        gb.Ah[head * 2 + 1] = h_hi + (size_t)head * BH;
        gb.Al[head * 2 + 1] = h_lo + (size_t)head * BH;
        gb.Bh[head * 2 + 1] = WhhT_h + (size_t)head * HG * H_DIM;
        gb.Bl[head * 2 + 1] = WhhT_l + (size_t)head * HG * H_DIM;
        gb.bias[head * 2 + 1] = gbhh + (size_t)head * HG;
        gb.C[head * 2 + 1] = gh2 + (size_t)head * B_DIM * HG;
      }
      gemm_mfma<<<dim3((HG / 128) * (B_DIM / 128), 4), blk, 0, stream>>>(
          gb, H_DIM, HG, HG, (long long)HG, HG / 128, B_DIM / 128);
      gru_combine_kernel<<<(2 * BH + 255) / 256, blk, 0, stream>>>(gi2, gh2, h2, h_hi, h_lo);
    }

    // logits GEMM, z=2: N=5001 (40 n-blocks), C into probs rows
    GemmS lb;
    for (int head = 0; head < NHEADS; ++head) {
      lb.Ah[head] = h_hi + (size_t)head * BH;
      lb.Al[head] = h_lo + (size_t)head * BH;
      lb.Bh[head] = hWT_h + (size_t)head * A_DIM * H_DIM;
      lb.Bl[head] = hWT_l + (size_t)head * A_DIM * H_DIM;
      lb.bias[head] = hb + (size_t)head * A_DIM;
      lb.C[head] = probs + (size_t)(head * NSTEPS + j) * A_DIM;
      lb.Ah[head + 2] = lb.Ah[head]; lb.Al[head + 2] = lb.Al[head];
      lb.Bh[head + 2] = lb.Bh[head]; lb.Bl[head + 2] = lb.Bl[head];
      lb.bias[head + 2] = lb.bias[head]; lb.C[head + 2] = lb.C[head];
    }
    gemm_mfma<<<dim3(40 * (B_DIM / 128), 2), blk, 0, stream>>>(
        lb, H_DIM, A_DIM, A_DIM, (long long)NHEADS * NSTEPS * A_DIM, 40, B_DIM / 128);

    uint32_t s00, s01, s10, s11;
    threefry2x32(hk[0][0], hk[0][1], 0u, (uint32_t)j, s00, s01);
    threefry2x32(hk[1][0], hk[1][1], 0u, (uint32_t)j, s10, s11);
    uint4 keys; keys.x = s00; keys.y = s01; keys.z = s10; keys.w = s11;
    sample_kernel<<<dim3(B_DIM, NHEADS), dim3(STH), 0, stream>>>(
        probs, xmask, indb, j, keys, cls, ae_w, cur_hi, cur_lo, (j < NSTEPS - 1) ? 1 : 0);
  }

  head_final_kernel<<<(NHEADS * B_DIM + 255) / 256, blk, 0, stream>>>(
      indb, Wmu, bmu, Wcov, bcov, alpha, matcp);
  final_out_kernel<<<(B_DIM * C_DIM + 255) / 256, blk, 0, stream>>>(matcp, out);
}